// Round 5
// baseline (828.423 us; speedup 1.0000x reference)
//
#include <hip/hip_runtime.h>

#define NN 128
#define NITER 300
#define NROUND 4   // bracket /5^4 = /625, then TWO exact active-set Newton steps
                   // (R1-proven config, absmax 4.88e-4 = output bf16 floor).
                   // FIXED path — no data-dependent exits (R4 lesson: at 1
                   // wave/SIMD, duration = max over samples; worst case rules).

typedef float float4v __attribute__((ext_vector_type(4)));

// ---- DPP wave-64 cross-lane helpers (R5-proven) ----
template<int CTRL>
__device__ __forceinline__ float dpp0(float x) {  // invalid lanes contribute 0
  return __int_as_float(__builtin_amdgcn_update_dpp(0, __float_as_int(x), CTRL, 0xF, 0xF, true));
}
template<int CTRL>
__device__ __forceinline__ float dppS(float x) {  // invalid lanes keep self
  int xi = __float_as_int(x);
  return __int_as_float(__builtin_amdgcn_update_dpp(xi, xi, CTRL, 0xF, 0xF, false));
}
__device__ __forceinline__ float bcast63(float x) {
  return __int_as_float(__builtin_amdgcn_readlane(__float_as_int(x), 63));
}
__device__ __forceinline__ float wsum(float x) {
  x += dpp0<0x111>(x); x += dpp0<0x112>(x); x += dpp0<0x114>(x);
  x += dpp0<0x118>(x); x += dpp0<0x142>(x); x += dpp0<0x143>(x);
  return bcast63(x);
}
__device__ __forceinline__ void wsum2(float& x, float& y) {  // two interleaved chains
  float a = x, b = y;
  a += dpp0<0x111>(a); b += dpp0<0x111>(b);
  a += dpp0<0x112>(a); b += dpp0<0x112>(b);
  a += dpp0<0x114>(a); b += dpp0<0x114>(b);
  a += dpp0<0x118>(a); b += dpp0<0x118>(b);
  a += dpp0<0x142>(a); b += dpp0<0x142>(b);
  a += dpp0<0x143>(a); b += dpp0<0x143>(b);
  x = bcast63(a); y = bcast63(b);
}
__device__ __forceinline__ void wsum4(float& a, float& b, float& c, float& d) {
  a += dpp0<0x111>(a); b += dpp0<0x111>(b); c += dpp0<0x111>(c); d += dpp0<0x111>(d);
  a += dpp0<0x112>(a); b += dpp0<0x112>(b); c += dpp0<0x112>(c); d += dpp0<0x112>(d);
  a += dpp0<0x114>(a); b += dpp0<0x114>(b); c += dpp0<0x114>(c); d += dpp0<0x114>(d);
  a += dpp0<0x118>(a); b += dpp0<0x118>(b); c += dpp0<0x118>(c); d += dpp0<0x118>(d);
  a += dpp0<0x142>(a); b += dpp0<0x142>(b); c += dpp0<0x142>(c); d += dpp0<0x142>(d);
  a += dpp0<0x143>(a); b += dpp0<0x143>(b); c += dpp0<0x143>(c); d += dpp0<0x143>(d);
  a = bcast63(a); b = bcast63(b); c = bcast63(c); d = bcast63(d);
}
__device__ __forceinline__ void wminmax(float& mn, float& mx) {  // interleaved
  mn = fminf(mn, dppS<0x111>(mn)); mx = fmaxf(mx, dppS<0x111>(mx));
  mn = fminf(mn, dppS<0x112>(mn)); mx = fmaxf(mx, dppS<0x112>(mx));
  mn = fminf(mn, dppS<0x114>(mn)); mx = fmaxf(mx, dppS<0x114>(mx));
  mn = fminf(mn, dppS<0x118>(mn)); mx = fmaxf(mx, dppS<0x118>(mx));
  mn = fminf(mn, dppS<0x142>(mn)); mx = fmaxf(mx, dppS<0x142>(mx));
  mn = fminf(mn, dppS<0x143>(mn)); mx = fmaxf(mx, dppS<0x143>(mx));
  mn = bcast63(mn); mx = bcast63(mx);
}

// ONE WAVE PER SAMPLE. Broadcasts via LDS (ds_read_b128 of a uniform address
// is a HW broadcast on the LDS pipe) instead of v_readlane on the VALU pipe:
// -128 VALU/iter in the matvec, -128 VALU/k-step in the Q-build. Plain scalar
// fma so Q stays AGPR-resident with direct VALU operands (no shuttles).
__launch_bounds__(64, 1)
__global__ void markowitz_kernel(const float* __restrict__ rets,
                                 const float* __restrict__ cov,
                                 const float* __restrict__ gam,
                                 const float* __restrict__ alp,
                                 float* __restrict__ out)
{
  const int b    = blockIdx.x;
  const int lane = threadIdx.x;          // block = exactly one wave (64)

  __shared__ __align__(16) float cbuf[2][NN];  // C-row stage, dbuf over k
  __shared__ __align__(16) float ybuf[2][NN];  // y stage, dbuf over it

  const float g   = gam[b];
  const float g2  = g * g;
  const float aab = fabsf(alp[b]);
  const float* cb = cov + (size_t)b * (NN * NN);

  // ---------- build Q = g2*C^T C + aab*I (rows lane / lane+64) ----------
  float accA[NN], accB[NN];
  #pragma unroll
  for (int u = 0; u < NN; ++u) { accA[u] = 0.f; accB[u] = 0.f; }

  const float* ap0 = cb + lane;
  const float* ap1 = cb + lane + 64;
  // 2-deep global prefetch + 1-ahead LDS stage
  float a0c = ap0[0],           a1c = ap1[0];            // k = 0
  float a0n = ap0[(size_t)NN],  a1n = ap1[(size_t)NN];   // k = 1
  cbuf[0][lane] = a0c; cbuf[0][64 + lane] = a1c;         // stage k = 0

  #pragma unroll 2
  for (int k = 0; k < NN; ++k) {
    const int cur = k & 1, nxt = cur ^ 1;
    cbuf[nxt][lane] = a0n; cbuf[nxt][64 + lane] = a1n;   // stage k+1
    const int kp = (k + 2 < NN) ? (k + 2) : (NN - 1);    // prefetch k+2
    float a0f = ap0[(size_t)kp * NN];
    float a1f = ap1[(size_t)kp * NN];
    #pragma unroll
    for (int j = 0; j < 32; ++j) {
      float4v cc = *(const float4v*)&cbuf[cur][4 * j];   // broadcast read
      accA[4*j+0] = fmaf(a0c, cc.x, accA[4*j+0]);
      accA[4*j+1] = fmaf(a0c, cc.y, accA[4*j+1]);
      accA[4*j+2] = fmaf(a0c, cc.z, accA[4*j+2]);
      accA[4*j+3] = fmaf(a0c, cc.w, accA[4*j+3]);
      accB[4*j+0] = fmaf(a1c, cc.x, accB[4*j+0]);
      accB[4*j+1] = fmaf(a1c, cc.y, accB[4*j+1]);
      accB[4*j+2] = fmaf(a1c, cc.z, accB[4*j+2]);
      accB[4*j+3] = fmaf(a1c, cc.w, accB[4*j+3]);
    }
    a0c = a0n; a1c = a1n; a0n = a0f; a1n = a1f;
  }

  // scale, diagonal, Frobenius^2 (4 partial chains)
  float ss0 = 0.f, ss1 = 0.f, ss2 = 0.f, ss3 = 0.f;
  #pragma unroll
  for (int u = 0; u < NN; ++u) {
    float qa = g2 * accA[u]; if (u == lane)      qa += aab;
    float qb = g2 * accB[u]; if (u == lane + 64) qb += aab;
    accA[u] = qa; accB[u] = qb;
    if (u & 1) { ss0 = fmaf(qa, qa, ss0); ss1 = fmaf(qb, qb, ss1); }
    else       { ss2 = fmaf(qa, qa, ss2); ss3 = fmaf(qb, qb, ss3); }
  }
  const float S    = wsum((ss0 + ss2) + (ss1 + ss3));
  const float step = 0.5f / sqrtf(S);    // 1/(2||Q||_F)
  const float sc   = 2.f * step;
  #pragma unroll
  for (int u = 0; u < NN; ++u) { accA[u] *= sc; accB[u] *= sc; }  // acc = 2*step*Q

  const float r2a = step * rets[b * NN + lane];
  const float r2b = step * rets[b * NN + 64 + lane];

  // ---------- FISTA, fully in-wave ----------
  float y0 = 1.f / 128.f, y1 = 1.f / 128.f;   // y coords (lane, lane+64)
  float w0p = y0, w1p = y1;                   // w_prev
  float t_f = 1.f;

  #pragma unroll 1
  for (int it = 0; it < NITER; ++it) {
    // matvec via LDS broadcast: 2 ds_write + 32 ds_read_b128 + 256 fma
    float* yb = ybuf[it & 1];
    yb[lane] = y0; yb[64 + lane] = y1;
    float pA0 = 0.f, pA1 = 0.f, pA2 = 0.f, pA3 = 0.f;
    float pB0 = 0.f, pB1 = 0.f, pB2 = 0.f, pB3 = 0.f;
    #pragma unroll
    for (int j = 0; j < 32; ++j) {
      float4v yy = *(const float4v*)&yb[4 * j];          // broadcast read
      pA0 = fmaf(accA[4*j+0], yy.x, pA0);
      pA1 = fmaf(accA[4*j+1], yy.y, pA1);
      pA2 = fmaf(accA[4*j+2], yy.z, pA2);
      pA3 = fmaf(accA[4*j+3], yy.w, pA3);
      pB0 = fmaf(accB[4*j+0], yy.x, pB0);
      pB1 = fmaf(accB[4*j+1], yy.y, pB1);
      pB2 = fmaf(accB[4*j+2], yy.z, pB2);
      pB3 = fmaf(accB[4*j+3], yy.w, pB3);
    }
    float v0 = y0 - ((pA0 + pA1) + (pA2 + pA3)) + r2a;   // v = y - step*grad
    float v1 = y1 - ((pB0 + pB1) + (pB2 + pB3)) + r2b;

    // projection onto {sum w=1, 0<=w<=1}: 4 rounds x 4-point bracket search
    float mn = fminf(v0, v1), mx = fmaxf(v0, v1);
    wminmax(mn, mx);
    float lo = mn - 1.0f;
    float W  = mx - lo;
    #pragma unroll 1
    for (int r = 0; r < NROUND; ++r) {
      float h  = W * 0.2f;
      float t1v = lo + h, t2v = lo + 2.f*h, t3v = lo + 3.f*h, t4v = lo + 4.f*h;
      float sa = __builtin_amdgcn_fmed3f(v0 - t1v, 0.f, 1.f)
               + __builtin_amdgcn_fmed3f(v1 - t1v, 0.f, 1.f);
      float sb = __builtin_amdgcn_fmed3f(v0 - t2v, 0.f, 1.f)
               + __builtin_amdgcn_fmed3f(v1 - t2v, 0.f, 1.f);
      float sc4 = __builtin_amdgcn_fmed3f(v0 - t3v, 0.f, 1.f)
               + __builtin_amdgcn_fmed3f(v1 - t3v, 0.f, 1.f);
      float sd = __builtin_amdgcn_fmed3f(v0 - t4v, 0.f, 1.f)
               + __builtin_amdgcn_fmed3f(v1 - t4v, 0.f, 1.f);
      wsum4(sa, sb, sc4, sd);
      float cnt = ((sa > 1.f ? 1.f : 0.f) + (sb > 1.f ? 1.f : 0.f))
                + ((sc4 > 1.f ? 1.f : 0.f) + (sd > 1.f ? 1.f : 0.f));
      lo = fmaf(cnt, h, lo);
      W  = h;
    }
    float tauf = lo + 0.5f * W;

    // two exact active-set Newton steps; second also produces w
    float w0 = 0.f, w1 = 0.f;
    #pragma unroll
    for (int e = 0; e < 2; ++e) {
      float z0 = v0 - tauf, z1 = v1 - tauf;
      bool fr0 = (z0 > 0.f) && (z0 < 1.0f);
      bool fr1 = (z1 > 0.f) && (z1 < 1.0f);
      bool cp0 = (z0 >= 1.0f), cp1 = (z1 >= 1.0f);
      float sfv = (fr0 ? v0 : 0.f) + (fr1 ? v1 : 0.f);
      float cnt = (fr0 ? 1.f : 0.f) + (fr1 ? 1.f : 0.f)
                + 1024.f * ((cp0 ? 1.f : 0.f) + (cp1 ? 1.f : 0.f));
      wsum2(sfv, cnt);
      float nu    = floorf(cnt * (1.f / 1024.f));
      float nfree = fmaxf(cnt - 1024.f * nu, 1.f);
      tauf = (sfv + nu - 1.f) * __builtin_amdgcn_rcpf(nfree);
      if (e == 1) {
        w0 = fr0 ? (v0 - tauf) : (cp0 ? 1.0f : 0.f);
        w1 = fr1 ? (v1 - tauf) : (cp1 ? 1.0f : 0.f);
      }
    }

    // FISTA momentum
    float tn   = 0.5f * (1.f + sqrtf(1.f + 4.f * t_f * t_f));
    float coef = (t_f - 1.f) * __builtin_amdgcn_rcpf(tn);
    y0 = w0 + coef * (w0 - w0p);
    y1 = w1 + coef * (w1 - w1p);
    w0p = w0; w1p = w1;
    t_f = tn;
  }

  out[(size_t)b * NN + lane]      = w0p;
  out[(size_t)b * NN + 64 + lane] = w1p;
}

extern "C" void kernel_launch(void* const* d_in, const int* in_sizes, int n_in,
                              void* d_out, int out_size, void* d_ws, size_t ws_size,
                              hipStream_t stream) {
  (void)n_in; (void)d_ws; (void)ws_size; (void)out_size;
  const float* rets = (const float*)d_in[0];
  const float* cov  = (const float*)d_in[1];
  const float* gam  = (const float*)d_in[2];
  const float* alp  = (const float*)d_in[3];
  float* out = (float*)d_out;
  const int B = in_sizes[0] / NN;   // 1024 waves, one sample each
  markowitz_kernel<<<B, 64, 0, stream>>>(rets, cov, gam, alp, out);
}

// Round 6
// 593.999 us; speedup vs baseline: 1.3947x; 1.3947x over previous
//
#include <hip/hip_runtime.h>

#define NN 128
#define NITER 300
#define NROUND 4   // 4 rounds x 4-point bracket (/625) + 2 exact Newton steps —
                   // the R0/R1-proven config (absmax 4.88e-4 = output bf16
                   // floor). FIXED path, no data-dependent exits (R4 lesson),
                   // no LDS in the hot loop (R5 lesson: LDS latency at 1
                   // wave/SIMD is a dead stall).

// ---- DPP wave-64 cross-lane helpers ----
template<int CTRL>
__device__ __forceinline__ float dpp0(float x) {  // invalid lanes contribute 0
  return __int_as_float(__builtin_amdgcn_update_dpp(0, __float_as_int(x), CTRL, 0xF, 0xF, true));
}
template<int CTRL>
__device__ __forceinline__ float dppS(float x) {  // invalid lanes keep self
  int xi = __float_as_int(x);
  return __int_as_float(__builtin_amdgcn_update_dpp(xi, xi, CTRL, 0xF, 0xF, false));
}
__device__ __forceinline__ float bcast63(float x) {
  return __int_as_float(__builtin_amdgcn_readlane(__float_as_int(x), 63));
}
__device__ __forceinline__ float rlane(float x, int l) {   // l literal after unroll
  return __int_as_float(__builtin_amdgcn_readlane(__float_as_int(x), l));
}
__device__ __forceinline__ float wsum(float x) {
  x += dpp0<0x111>(x); x += dpp0<0x112>(x); x += dpp0<0x114>(x);
  x += dpp0<0x118>(x); x += dpp0<0x142>(x); x += dpp0<0x143>(x);
  return bcast63(x);
}
// 4 interleaved no-broadcast chains; cnt(#s>1) computed on lane63's totals,
// ONE bcast63 instead of four (R6: serial-chain tail cut).
__device__ __forceinline__ float wsum4_cnt(float a, float b, float c, float d) {
  a += dpp0<0x111>(a); b += dpp0<0x111>(b); c += dpp0<0x111>(c); d += dpp0<0x111>(d);
  a += dpp0<0x112>(a); b += dpp0<0x112>(b); c += dpp0<0x112>(c); d += dpp0<0x112>(d);
  a += dpp0<0x114>(a); b += dpp0<0x114>(b); c += dpp0<0x114>(c); d += dpp0<0x114>(d);
  a += dpp0<0x118>(a); b += dpp0<0x118>(b); c += dpp0<0x118>(c); d += dpp0<0x118>(d);
  a += dpp0<0x142>(a); b += dpp0<0x142>(b); c += dpp0<0x142>(c); d += dpp0<0x142>(d);
  a += dpp0<0x143>(a); b += dpp0<0x143>(b); c += dpp0<0x143>(c); d += dpp0<0x143>(d);
  float cnt = ((a > 1.f ? 1.f : 0.f) + (b > 1.f ? 1.f : 0.f))
            + ((c > 1.f ? 1.f : 0.f) + (d > 1.f ? 1.f : 0.f));
  return bcast63(cnt);
}
// 2 interleaved no-broadcast chains; tau computed on lane63's totals,
// ONE bcast63 instead of two. Bit-identical inputs -> bit-identical tau.
__device__ __forceinline__ float wsum2_tau(float sfv, float cnt) {
  float a = sfv, b = cnt;
  a += dpp0<0x111>(a); b += dpp0<0x111>(b);
  a += dpp0<0x112>(a); b += dpp0<0x112>(b);
  a += dpp0<0x114>(a); b += dpp0<0x114>(b);
  a += dpp0<0x118>(a); b += dpp0<0x118>(b);
  a += dpp0<0x142>(a); b += dpp0<0x142>(b);
  a += dpp0<0x143>(a); b += dpp0<0x143>(b);
  float nu    = floorf(b * (1.f / 1024.f));
  float nfree = fmaxf(b - 1024.f * nu, 1.f);
  float tau   = (a + nu - 1.f) * __builtin_amdgcn_rcpf(nfree);
  return bcast63(tau);
}
__device__ __forceinline__ void wminmax(float& mn, float& mx) {  // interleaved
  mn = fminf(mn, dppS<0x111>(mn)); mx = fmaxf(mx, dppS<0x111>(mx));
  mn = fminf(mn, dppS<0x112>(mn)); mx = fmaxf(mx, dppS<0x112>(mx));
  mn = fminf(mn, dppS<0x114>(mn)); mx = fmaxf(mx, dppS<0x114>(mx));
  mn = fminf(mn, dppS<0x118>(mn)); mx = fmaxf(mx, dppS<0x118>(mx));
  mn = fminf(mn, dppS<0x142>(mn)); mx = fmaxf(mx, dppS<0x142>(mx));
  mn = fminf(mn, dppS<0x143>(mn)); mx = fmaxf(mx, dppS<0x143>(mx));
  mn = bcast63(mn); mx = bcast63(mx);
}

// ONE WAVE PER SAMPLE (proven best). Lane owns rows {lane, lane+64}. Scalar
// fma (Q AGPR-resident, direct operands). R6: readlanes BLOCK-PREFETCHED
// 16-ahead so the v_readlane(SGPR-write) -> v_fma(SGPR-read) RAW hazard is
// covered by ~32 intervening instructions instead of ~2.
__launch_bounds__(64, 1)
__global__ void markowitz_kernel(const float* __restrict__ rets,
                                 const float* __restrict__ cov,
                                 const float* __restrict__ gam,
                                 const float* __restrict__ alp,
                                 float* __restrict__ out)
{
  const int b    = blockIdx.x;
  const int lane = threadIdx.x;          // block = exactly one wave (64)

  const float g   = gam[b];
  const float g2  = g * g;
  const float aab = fabsf(alp[b]);
  const float* cb = cov + (size_t)b * (NN * NN);

  // ---------- build Q = g2*C^T C + aab*I (rows lane / lane+64) ----------
  float accA[NN], accB[NN];
  #pragma unroll
  for (int u = 0; u < NN; ++u) { accA[u] = 0.f; accB[u] = 0.f; }

  const float* ap0 = cb + lane;
  const float* ap1 = cb + lane + 64;
  #pragma unroll 2
  for (int k = 0; k < NN; ++k) {
    float a0 = ap0[(size_t)k * NN];      // C[k][lane]      (coalesced)
    float a1 = ap1[(size_t)k * NN];      // C[k][lane+64]
    // block-prefetched broadcasts: 16 rlanes issued a block ahead of use
    float sh0[8], sh1[8];
    #pragma unroll
    for (int j = 0; j < 8; ++j) { sh0[j] = rlane(a0, j); sh1[j] = rlane(a1, j); }
    #pragma unroll
    for (int blk = 0; blk < 8; ++blk) {
      float nh0[8], nh1[8];
      if (blk < 7) {
        #pragma unroll
        for (int j = 0; j < 8; ++j) {
          nh0[j] = rlane(a0, 8 * blk + 8 + j);
          nh1[j] = rlane(a1, 8 * blk + 8 + j);
        }
      }
      #pragma unroll
      for (int j = 0; j < 8; ++j) {
        const int u = 8 * blk + j;
        accA[u]      = fmaf(a0, sh0[j], accA[u]);
        accA[64 + u] = fmaf(a0, sh1[j], accA[64 + u]);
        accB[u]      = fmaf(a1, sh0[j], accB[u]);
        accB[64 + u] = fmaf(a1, sh1[j], accB[64 + u]);
      }
      if (blk < 7) {
        #pragma unroll
        for (int j = 0; j < 8; ++j) { sh0[j] = nh0[j]; sh1[j] = nh1[j]; }
      }
    }
  }

  // scale, diagonal, Frobenius^2 (4 partial chains)
  float ss0 = 0.f, ss1 = 0.f, ss2 = 0.f, ss3 = 0.f;
  #pragma unroll
  for (int u = 0; u < NN; ++u) {
    float qa = g2 * accA[u]; if (u == lane)      qa += aab;
    float qb = g2 * accB[u]; if (u == lane + 64) qb += aab;
    accA[u] = qa; accB[u] = qb;
    if (u & 1) { ss0 = fmaf(qa, qa, ss0); ss1 = fmaf(qb, qb, ss1); }
    else       { ss2 = fmaf(qa, qa, ss2); ss3 = fmaf(qb, qb, ss3); }
  }
  const float S    = wsum((ss0 + ss2) + (ss1 + ss3));
  const float step = 0.5f / sqrtf(S);    // 1/(2||Q||_F)
  const float sc   = 2.f * step;
  #pragma unroll
  for (int u = 0; u < NN; ++u) { accA[u] *= sc; accB[u] *= sc; }  // acc = 2*step*Q

  const float r2a = step * rets[b * NN + lane];
  const float r2b = step * rets[b * NN + 64 + lane];

  // ---------- FISTA, fully in-wave ----------
  float y0 = 1.f / 128.f, y1 = 1.f / 128.f;   // y coords (lane, lane+64)
  float w0p = y0, w1p = y1;                   // w_prev
  float t_f = 1.f;

  #pragma unroll 1
  for (int it = 0; it < NITER; ++it) {
    // momentum scalars hoisted: depend only on t_f -> sqrt/rcp latency hides
    // under the matvec below (same fp32 ops, same values as before)
    float tn   = 0.5f * (1.f + sqrtf(1.f + 4.f * t_f * t_f));
    float coef = (t_f - 1.f) * __builtin_amdgcn_rcpf(tn);

    // matvec: 4 independent fma chains; readlanes block-prefetched 16-ahead
    float pA0 = 0.f, pA1 = 0.f, pB0 = 0.f, pB1 = 0.f;
    {
      float sh0[8], sh1[8];
      #pragma unroll
      for (int j = 0; j < 8; ++j) { sh0[j] = rlane(y0, j); sh1[j] = rlane(y1, j); }
      #pragma unroll
      for (int blk = 0; blk < 8; ++blk) {
        float nh0[8], nh1[8];
        if (blk < 7) {
          #pragma unroll
          for (int j = 0; j < 8; ++j) {
            nh0[j] = rlane(y0, 8 * blk + 8 + j);
            nh1[j] = rlane(y1, 8 * blk + 8 + j);
          }
        }
        #pragma unroll
        for (int j = 0; j < 8; ++j) {
          const int u = 8 * blk + j;
          pA0 = fmaf(accA[u],      sh0[j], pA0);
          pA1 = fmaf(accA[64 + u], sh1[j], pA1);
          pB0 = fmaf(accB[u],      sh0[j], pB0);
          pB1 = fmaf(accB[64 + u], sh1[j], pB1);
        }
        if (blk < 7) {
          #pragma unroll
          for (int j = 0; j < 8; ++j) { sh0[j] = nh0[j]; sh1[j] = nh1[j]; }
        }
      }
    }
    float v0 = y0 - (pA0 + pA1) + r2a;   // v = y - step*grad
    float v1 = y1 - (pB0 + pB1) + r2b;

    // projection onto {sum w=1, 0<=w<=1}: 4 rounds x 4-point bracket search
    float mn = fminf(v0, v1), mx = fmaxf(v0, v1);
    wminmax(mn, mx);
    float lo = mn - 1.0f;
    float W  = mx - lo;
    #pragma unroll 1
    for (int r = 0; r < NROUND; ++r) {
      float h  = W * 0.2f;
      float t1v = lo + h, t2v = lo + 2.f*h, t3v = lo + 3.f*h, t4v = lo + 4.f*h;
      float sa = __builtin_amdgcn_fmed3f(v0 - t1v, 0.f, 1.f)
               + __builtin_amdgcn_fmed3f(v1 - t1v, 0.f, 1.f);
      float sb = __builtin_amdgcn_fmed3f(v0 - t2v, 0.f, 1.f)
               + __builtin_amdgcn_fmed3f(v1 - t2v, 0.f, 1.f);
      float sc4 = __builtin_amdgcn_fmed3f(v0 - t3v, 0.f, 1.f)
               + __builtin_amdgcn_fmed3f(v1 - t3v, 0.f, 1.f);
      float sd = __builtin_amdgcn_fmed3f(v0 - t4v, 0.f, 1.f)
               + __builtin_amdgcn_fmed3f(v1 - t4v, 0.f, 1.f);
      float cnt = wsum4_cnt(sa, sb, sc4, sd);   // ONE broadcast per round
      lo = fmaf(cnt, h, lo);
      W  = h;
    }
    float tauf = lo + 0.5f * W;

    // two exact active-set Newton steps; second also produces w
    float w0 = 0.f, w1 = 0.f;
    #pragma unroll
    for (int e = 0; e < 2; ++e) {
      float z0 = v0 - tauf, z1 = v1 - tauf;
      bool fr0 = (z0 > 0.f) && (z0 < 1.0f);
      bool fr1 = (z1 > 0.f) && (z1 < 1.0f);
      bool cp0 = (z0 >= 1.0f), cp1 = (z1 >= 1.0f);
      float sfv = (fr0 ? v0 : 0.f) + (fr1 ? v1 : 0.f);
      float cnt = (fr0 ? 1.f : 0.f) + (fr1 ? 1.f : 0.f)
                + 1024.f * ((cp0 ? 1.f : 0.f) + (cp1 ? 1.f : 0.f));
      tauf = wsum2_tau(sfv, cnt);               // ONE broadcast per step
      if (e == 1) {
        w0 = fr0 ? (v0 - tauf) : (cp0 ? 1.0f : 0.f);
        w1 = fr1 ? (v1 - tauf) : (cp1 ? 1.0f : 0.f);
      }
    }

    // FISTA momentum (scalars precomputed at iteration top)
    y0 = w0 + coef * (w0 - w0p);
    y1 = w1 + coef * (w1 - w1p);
    w0p = w0; w1p = w1;
    t_f = tn;
  }

  out[(size_t)b * NN + lane]      = w0p;
  out[(size_t)b * NN + 64 + lane] = w1p;
}

extern "C" void kernel_launch(void* const* d_in, const int* in_sizes, int n_in,
                              void* d_out, int out_size, void* d_ws, size_t ws_size,
                              hipStream_t stream) {
  (void)n_in; (void)d_ws; (void)ws_size; (void)out_size;
  const float* rets = (const float*)d_in[0];
  const float* cov  = (const float*)d_in[1];
  const float* gam  = (const float*)d_in[2];
  const float* alp  = (const float*)d_in[3];
  float* out = (float*)d_out;
  const int B = in_sizes[0] / NN;   // 1024 waves, one sample each
  markowitz_kernel<<<B, 64, 0, stream>>>(rets, cov, gam, alp, out);
}